// Round 7
// baseline (51118.890 us; speedup 1.0000x reference)
//
#include <hip/hip_runtime.h>

// ResLSTM: T=512, B=128, IN=H=1024, L=4.
// R7: WEIGHTS-IN-REGISTERS persistent kernel. R3/R5/R6 all hit the same
// ~70us/superstep wall = re-streaming 92 MB of weights from beyond L2 every
// superstep at ~1 TB/s (R4 counters). Fix: hold all weights in the register
// file (134 MB chip-wide > 92 MB). 256 WGs (4 layers x 64 col-tiles), 4 waves,
// 1 wave/SIMD, 352 VGPR/lane of bf16 weight frags loaded ONCE. Grid-persistent
// with a 2-level atomic tree barrier; state exchanged via sc0/sc1 write-through
// stores + per-superstep acquire-fence (invalidate can't hurt register-resident
// weights). Partial gate sums (each wave owns a stride-4 k-quarter) combined
// per m-tile through LDS.

#define TT 512
#define BB 128
#define IN_D 1024
#define HH 1024
#define LL 4
#define G3 3072
#define NSUPER (TT + LL - 1)
#define SLOT (BB * HH)
#define SLOT_ALL (LL * SLOT)
#define NWG 256

typedef __attribute__((ext_vector_type(8))) __bf16 bf16x8;
typedef __attribute__((ext_vector_type(4))) __bf16 bf16x4;
typedef __attribute__((ext_vector_type(4))) float f32x4;

__device__ __forceinline__ f32x4 mfma16(bf16x8 a, bf16x8 b, f32x4 c) {
    return __builtin_amdgcn_mfma_f32_16x16x32_bf16(a, b, c, 0, 0, 0);
}

__device__ __forceinline__ bf16x8 ldb(const __bf16* p, int k) {
    return *reinterpret_cast<const bf16x8*>(p + k);
}

__device__ __forceinline__ bf16x8 cvt8(float4 u, float4 v) {
    bf16x8 r;
    r[0] = (__bf16)u.x; r[1] = (__bf16)u.y; r[2] = (__bf16)u.z; r[3] = (__bf16)u.w;
    r[4] = (__bf16)v.x; r[5] = (__bf16)v.y; r[6] = (__bf16)v.z; r[7] = (__bf16)v.w;
    return r;
}

__device__ __forceinline__ float sigm(float v) { return 1.f / (1.f + __expf(-v)); }
__device__ __forceinline__ float tanh_fast(float v) { return 1.f - 2.f / (1.f + __expf(2.f * v)); }

__device__ __forceinline__ unsigned short bf16bits(float f) {
    __bf16 h = (__bf16)f;
    return __builtin_bit_cast(unsigned short, h);
}

// coherent (write-through to L3) stores for cross-XCD state exchange
__device__ __forceinline__ void st_f32_sc(float* p, float v) {
    asm volatile("global_store_dword %0, %1, off sc0 sc1" :: "v"(p), "v"(v) : "memory");
}
__device__ __forceinline__ void st_b16_sc(__bf16* p, unsigned v) {
    asm volatile("global_store_short %0, %1, off sc0 sc1" :: "v"(p), "v"(v) : "memory");
}

// ---- fused gates weight: Wg[j][n][k], k<1024:Wii, k<2048:Wih, else:Wic ----
__global__ void k_conv_gates(const float* __restrict__ Wii,
                             const float* __restrict__ Wic,
                             const float* __restrict__ Wih,
                             __bf16* __restrict__ Wg) {
    const unsigned total = (unsigned)LL * G3 * G3;
    const unsigned stride = gridDim.x * blockDim.x * 4u;
    for (unsigned idx = (blockIdx.x * blockDim.x + threadIdx.x) * 4u; idx < total; idx += stride) {
        unsigned row = idx / G3;
        int k = (int)(idx - row * G3);
        const float* src; int ks;
        if (k < 1024)      { src = Wii; ks = k; }
        else if (k < 2048) { src = Wih; ks = k - 1024; }
        else               { src = Wic; ks = k - 2048; }
        float4 v = *reinterpret_cast<const float4*>(src + (size_t)row * 1024 + ks);
        bf16x4 o;
        o[0] = (__bf16)v.x; o[1] = (__bf16)v.y; o[2] = (__bf16)v.z; o[3] = (__bf16)v.w;
        *reinterpret_cast<bf16x4*>(Wg + idx) = o;
    }
}

__global__ void k_conv_plain(const float* __restrict__ s, __bf16* __restrict__ d, unsigned total) {
    const unsigned stride = gridDim.x * blockDim.x * 4u;
    for (unsigned idx = (blockIdx.x * blockDim.x + threadIdx.x) * 4u; idx < total; idx += stride) {
        float4 v = *reinterpret_cast<const float4*>(s + idx);
        bf16x4 o;
        o[0] = (__bf16)v.x; o[1] = (__bf16)v.y; o[2] = (__bf16)v.z; o[3] = (__bf16)v.w;
        *reinterpret_cast<bf16x4*>(d + idx) = o;
    }
}

__global__ void k_bias(const float* __restrict__ bii, const float* __restrict__ bic,
                       const float* __restrict__ bih, const float* __restrict__ bhh,
                       float* __restrict__ bsum) {
    int i = blockIdx.x * blockDim.x + threadIdx.x;
    int j = i >> 12, n = i & 4095;
    if (j >= LL) return;
    if (n < G3) bsum[j * 4096 + n] = bii[j * G3 + n] + bih[j * G3 + n] + bic[j * G3 + n];
    else        bsum[j * 4096 + n] = bhh[j * HH + (n - G3)];
}

// hidden [2L,B,H] -> parity-1 slots ("t = -1")
__global__ void k_init(const float* __restrict__ hidden,
                       float* __restrict__ cbufF, __bf16* __restrict__ hb, __bf16* __restrict__ cb) {
    const unsigned stride = gridDim.x * blockDim.x;
    for (unsigned i = blockIdx.x * blockDim.x + threadIdx.x; i < SLOT_ALL; i += stride) {
        float hv = hidden[i];
        float cv = hidden[SLOT_ALL + i];
        hb[SLOT_ALL + i] = (__bf16)hv;
        cb[SLOT_ALL + i] = (__bf16)cv;
        cbufF[SLOT_ALL + i] = cv;
    }
}

__global__ void k_final(const float* __restrict__ hfin, const float* __restrict__ cbufF,
                        float* __restrict__ out_tail) {
    const unsigned stride = gridDim.x * blockDim.x;
    for (unsigned i = blockIdx.x * blockDim.x + threadIdx.x; i < SLOT_ALL; i += stride) {
        out_tail[i] = hfin[i];
        out_tail[SLOT_ALL + i] = cbufF[SLOT_ALL + i];
    }
}

// Persistent: grid (LL, 64) x 256 threads. j = blockIdx.x (layer), n0 = blockIdx.y*16.
// Wave w holds weight frags for gate-kfrags {4q+w}: wI/wF/wO[24], wC/wR[8] (352 VGPR).
// Per superstep, per m (16 rows): 24 A-frag loads -> 88 MFMAs (partial sums over the
// wave's k-quarter); partials combined via LDS; consumer wave (m>>1) does the LSTM
// pointwise and sc1-stores the new state.
__global__ __launch_bounds__(256, 1) void k_persist(
    const float* __restrict__ x,
    const __bf16* __restrict__ Wg,
    const __bf16* __restrict__ Whh,
    const __bf16* __restrict__ Wir,
    const float* __restrict__ bsum,
    float* __restrict__ cbufF,
    __bf16* __restrict__ hb,
    __bf16* __restrict__ cb,
    float* __restrict__ hfin,
    float* __restrict__ dout,
    unsigned* __restrict__ bar)   // bar[0]=root, bar[16+16*g]=group counters
{
    __shared__ __align__(16) char smem[2 * 20480];   // 40 KiB partial-sum exchange

    const int j = blockIdx.x;
    const int n0 = blockIdx.y * 16;
    const int tid = threadIdx.x;
    const int lane = tid & 63;
    const int w = tid >> 6;
    const int lrow = lane & 15;
    const int kgrp = lane >> 4;
    const int wgid = (int)(blockIdx.x + LL * blockIdx.y);
    const int col = n0 + lrow;

    // ---- load weight fragments into registers (once) ----
    bf16x8 wI[24], wF[24], wO[24], wC[8], wR[8];
    {
        const __bf16* Wgj = Wg + (size_t)j * G3 * G3;
        #pragma unroll
        for (int q = 0; q < 24; ++q) {
            const size_t ko = (size_t)(4 * q + w) * 32 + kgrp * 8;
            wI[q] = *(const bf16x8*)(Wgj + (size_t)(col) * G3 + ko);
            wF[q] = *(const bf16x8*)(Wgj + (size_t)(1024 + col) * G3 + ko);
            wO[q] = *(const bf16x8*)(Wgj + (size_t)(2048 + col) * G3 + ko);
        }
        #pragma unroll
        for (int q = 0; q < 8; ++q) {
            const size_t ko = (size_t)(4 * q + w) * 32 + kgrp * 8;
            wC[q] = *(const bf16x8*)(Whh + (size_t)j * HH * HH + (size_t)col * HH + ko);
            wR[q] = *(const bf16x8*)(Wir + (size_t)j * HH * IN_D + (size_t)col * IN_D + ko);
        }
    }
    const float b_i = bsum[j * 4096 + col];
    const float b_f = bsum[j * 4096 + HH + col];
    const float b_o = bsum[j * 4096 + 2 * HH + col];
    const float b_c = bsum[j * 4096 + G3 + col];

    const int ofs = 32 * w + 8 * kgrp;       // per-lane element offset in a 1024-row

    for (int s = 0; s < NSUPER; ++s) {
        const int t = s - j;
        if ((unsigned)t < TT) {
            const int p = t & 1, pp = p ^ 1;
            const float*  cFsrc = cbufF + (size_t)pp * SLOT_ALL + (size_t)j * SLOT;
            float*        cFdst = cbufF + (size_t)p  * SLOT_ALL + (size_t)j * SLOT;
            const __bf16* hP = hb + (size_t)pp * SLOT_ALL + (size_t)j * SLOT;
            const __bf16* cP = cb + (size_t)pp * SLOT_ALL + (size_t)j * SLOT;
            const __bf16* outP = (j == 0) ? hP
                                : hb + (size_t)p * SLOT_ALL + (size_t)(j - 1) * SLOT;
            const float* xP = x + (size_t)t * SLOT;
            __bf16* hD = hb + (size_t)p * SLOT_ALL + (size_t)j * SLOT;
            __bf16* cD = cb + (size_t)p * SLOT_ALL + (size_t)j * SLOT;

            for (int m = 0; m < 8; ++m) {
                const int rowb = 16 * m + lrow;
                const __bf16* aO = outP + (size_t)rowb * HH + ofs;
                const float*  aX = xP   + (size_t)rowb * HH + ofs;
                const __bf16* aH = hP   + (size_t)rowb * HH + ofs;
                const __bf16* aC = cP   + (size_t)rowb * HH + ofs;

                f32x4 vI = {0,0,0,0}, vF = {0,0,0,0}, vO = {0,0,0,0},
                      vC = {0,0,0,0}, vR = {0,0,0,0};

                if (j > 0) {
                    #pragma unroll
                    for (int q = 0; q < 8; ++q) {
                        bf16x8 a = ldb(aO, 128 * q);
                        vI = mfma16(a, wI[q], vI); vF = mfma16(a, wF[q], vF);
                        vO = mfma16(a, wO[q], vO); vR = mfma16(a, wR[q], vR);
                    }
                } else {
                    #pragma unroll
                    for (int q = 0; q < 8; ++q) {
                        float4 u  = *(const float4*)(aX + 128 * q);
                        float4 v2 = *(const float4*)(aX + 128 * q + 4);
                        bf16x8 a = cvt8(u, v2);
                        vI = mfma16(a, wI[q], vI); vF = mfma16(a, wF[q], vF);
                        vO = mfma16(a, wO[q], vO); vR = mfma16(a, wR[q], vR);
                    }
                }
                #pragma unroll
                for (int q = 0; q < 8; ++q) {
                    bf16x8 a = ldb(aH, 128 * q);
                    vI = mfma16(a, wI[8 + q], vI); vF = mfma16(a, wF[8 + q], vF);
                    vO = mfma16(a, wO[8 + q], vO); vC = mfma16(a, wC[q], vC);
                }
                #pragma unroll
                for (int q = 0; q < 8; ++q) {
                    bf16x8 a = ldb(aC, 128 * q);
                    vI = mfma16(a, wI[16 + q], vI); vF = mfma16(a, wF[16 + q], vF);
                    vO = mfma16(a, wO[16 + q], vO);
                }

                // exchange partials (each wave's k-quarter) through LDS
                float* exw = (float*)(smem + (m & 1) * 20480) + w * 1280 + lane * 4;
                *(f32x4*)(exw +    0) = vI;
                *(f32x4*)(exw +  256) = vF;
                *(f32x4*)(exw +  512) = vO;
                *(f32x4*)(exw +  768) = vC;
                *(f32x4*)(exw + 1024) = vR;
                __syncthreads();

                if (w == (m >> 1)) {
                    f32x4 sI = {0,0,0,0}, sF = {0,0,0,0}, sO = {0,0,0,0},
                          sC = {0,0,0,0}, sR = {0,0,0,0};
                    #pragma unroll
                    for (int ww = 0; ww < 4; ++ww) {
                        const float* eb = (const float*)(smem + (m & 1) * 20480) + ww * 1280 + lane * 4;
                        sI += *(const f32x4*)(eb);
                        sF += *(const f32x4*)(eb + 256);
                        sO += *(const f32x4*)(eb + 512);
                        sC += *(const f32x4*)(eb + 768);
                        sR += *(const f32x4*)(eb + 1024);
                    }
                    #pragma unroll
                    for (int r = 0; r < 4; ++r) {
                        const int row = 16 * m + 4 * kgrp + r;
                        const size_t o = (size_t)row * HH + col;
                        float iv = sI[r] + b_i;
                        float fv = sF[r] + b_f;
                        float ov = sO[r] + b_o;
                        float cg = tanh_fast(sC[r] + b_c);
                        float cold = cFsrc[o];
                        float cy = sigm(fv) * cold + sigm(iv) * cg;
                        float hy = sigm(ov) * (tanh_fast(cy) + sR[r]);
                        st_f32_sc(cFdst + o, cy);
                        st_b16_sc(hD + o, (unsigned)bf16bits(hy));
                        st_b16_sc(cD + o, (unsigned)bf16bits(cy));
                        if (j == LL - 1) dout[(size_t)t * SLOT + o] = hy;
                        if (t == TT - 1) hfin[(size_t)j * SLOT + o] = hy;
                    }
                }
            }
        }

        // ---- grid barrier (2-level tree) + coherence ----
        __syncthreads();   // drains each wave's vmem (incl. sc1 stores) before barrier
        if (tid == 0) {
            unsigned* grp = bar + 16 + 16 * (wgid >> 4);
            // acq_rel: publishes this WG's L2 (release) and syncs group line (acquire)
            unsigned old = __hip_atomic_fetch_add(grp, 1u, __ATOMIC_ACQ_REL,
                                                  __HIP_MEMORY_SCOPE_AGENT);
            if (old == 16u * (unsigned)(s + 1) - 1u)
                __hip_atomic_fetch_add(bar, 1u, __ATOMIC_RELEASE,
                                       __HIP_MEMORY_SCOPE_AGENT);
            while (__hip_atomic_load(bar, __ATOMIC_RELAXED,
                                     __HIP_MEMORY_SCOPE_AGENT) < 16u * (unsigned)(s + 1))
                __builtin_amdgcn_s_sleep(4);
        }
        __syncthreads();
        // acquire: invalidate stale clean lines (weights live in registers -> immune)
        __builtin_amdgcn_fence(__ATOMIC_ACQUIRE, "agent");
    }
}

extern "C" void kernel_launch(void* const* d_in, const int* in_sizes, int n_in,
                              void* d_out, int out_size, void* d_ws, size_t ws_size,
                              hipStream_t stream) {
    const float* x      = (const float*)d_in[0];
    const float* hidden = (const float*)d_in[1];
    const float* Wii    = (const float*)d_in[2];
    const float* Wic    = (const float*)d_in[3];
    const float* Wih    = (const float*)d_in[4];
    const float* bii    = (const float*)d_in[5];
    const float* bic    = (const float*)d_in[6];
    const float* bih    = (const float*)d_in[7];
    const float* Whh    = (const float*)d_in[8];
    const float* bhh    = (const float*)d_in[9];
    const float* Wir    = (const float*)d_in[10];
    float* out = (float*)d_out;

    // ws layout (bytes):
    //   Wg     @ 0          75,497,472
    //   Whh_b  @ 75497472    8,388,608
    //   Wir_b  @ 83886080    8,388,608
    //   cbufF  @ 92274688    4,194,304
    //   bsum   @ 96468992       65,536
    //   hb     @ 96534528    2,097,152
    //   cb     @ 98631680    2,097,152
    //   hfin   @ 100728832   2,097,152
    //   bar    @ 102825984        4,096
    char* ws = (char*)d_ws;
    __bf16* Wg    = (__bf16*)(ws);
    __bf16* Whh_b = (__bf16*)(ws + 75497472);
    __bf16* Wir_b = (__bf16*)(ws + 83886080);
    float*  cbufF = (float*)(ws + 92274688);
    float*  bsum  = (float*)(ws + 96468992);
    __bf16* hb    = (__bf16*)(ws + 96534528);
    __bf16* cb    = (__bf16*)(ws + 98631680);
    float*  hfin  = (float*)(ws + 100728832);
    unsigned* bar = (unsigned*)(ws + 102825984);

    hipMemsetAsync(bar, 0, 4096, stream);
    k_conv_gates<<<4096, 256, 0, stream>>>(Wii, Wic, Wih, Wg);
    k_conv_plain<<<2048, 256, 0, stream>>>(Whh, Whh_b, (unsigned)(LL * HH * HH));
    k_conv_plain<<<2048, 256, 0, stream>>>(Wir, Wir_b, (unsigned)(LL * HH * IN_D));
    k_bias<<<64, 256, 0, stream>>>(bii, bic, bih, bhh, bsum);
    k_init<<<1024, 256, 0, stream>>>(hidden, cbufF, hb, cb);

    dim3 grid(LL, 64), block(256);
    k_persist<<<grid, block, 0, stream>>>(x, Wg, Whh_b, Wir_b, bsum,
                                          cbufF, hb, cb, hfin, out, bar);

    k_final<<<1024, 256, 0, stream>>>(hfin, cbufF, out + (size_t)TT * SLOT);
}

// Round 8
// 45434.976 us; speedup vs baseline: 1.1251x; 1.1251x over previous
//
#include <hip/hip_runtime.h>

// ResLSTM: T=512, B=128, IN=H=1024, L=4.
// R8: weights-in-registers persistent kernel (R7 mechanism, proven: FETCH 30.6->2.9GB)
// with the global spin barrier (R7's 95% overhead) replaced by pipelined
// producer/consumer FLAGS: single-writer sc-stores + 64-lane coherent polls.
// Deps of (j,t): done[j-1][t], done[j][t-1], done[j+1][t-4] (4-slot state buffers).
// Layers run with elastic skew; no chip-wide convergence. Weights read once
// directly from f32 inputs (no pre-pass kernels); ws shrinks to ~17 MB.

#define TT 512
#define BB 128
#define IN_D 1024
#define HH 1024
#define LL 4
#define G3 3072
#define SLOT (BB * HH)        // 131072
#define SLOT_ALL (LL * SLOT)  // 524288
#define NSL 4                 // state time-slots
#define NFS 8                 // flag time-slots (2x NSL: no ABA)

typedef __attribute__((ext_vector_type(8))) __bf16 bf16x8;
typedef __attribute__((ext_vector_type(4))) float f32x4;

__device__ __forceinline__ f32x4 mfma16(bf16x8 a, bf16x8 b, f32x4 c) {
    return __builtin_amdgcn_mfma_f32_16x16x32_bf16(a, b, c, 0, 0, 0);
}
__device__ __forceinline__ bf16x8 ldb(const __bf16* p, int k) {
    return *reinterpret_cast<const bf16x8*>(p + k);
}
__device__ __forceinline__ bf16x8 cvt8(float4 u, float4 v) {
    bf16x8 r;
    r[0] = (__bf16)u.x; r[1] = (__bf16)u.y; r[2] = (__bf16)u.z; r[3] = (__bf16)u.w;
    r[4] = (__bf16)v.x; r[5] = (__bf16)v.y; r[6] = (__bf16)v.z; r[7] = (__bf16)v.w;
    return r;
}
__device__ __forceinline__ bf16x8 cvt8p(const float* p) {
    float4 u = *reinterpret_cast<const float4*>(p);
    float4 v = *reinterpret_cast<const float4*>(p + 4);
    return cvt8(u, v);
}
__device__ __forceinline__ float sigm(float v) { return 1.f / (1.f + __expf(-v)); }
__device__ __forceinline__ float tanh_fast(float v) { return 1.f - 2.f / (1.f + __expf(2.f * v)); }
__device__ __forceinline__ unsigned bf16bits(float f) {
    __bf16 h = (__bf16)f;
    return (unsigned)__builtin_bit_cast(unsigned short, h);
}

// write-through coherent stores (visible at coherence point on vmcnt retire)
__device__ __forceinline__ void st_f32_sc(float* p, float v) {
    asm volatile("global_store_dword %0, %1, off sc0 sc1" :: "v"(p), "v"(v) : "memory");
}
__device__ __forceinline__ void st_b16_sc(__bf16* p, unsigned v) {
    asm volatile("global_store_short %0, %1, off sc0 sc1" :: "v"(p), "v"(v) : "memory");
}

// 64-lane flag-group wait: lane i polls flags[i] (one flag per producer WG)
__device__ __forceinline__ void waitg(const int* p, int tgt) {
    const int* q = p + (threadIdx.x & 63);
    for (;;) {
        int v;
        asm volatile("global_load_dword %0, %1, off sc0 sc1\n\ts_waitcnt vmcnt(0)"
                     : "=v"(v) : "v"(q) : "memory");
        if (__all(v >= tgt)) return;
        __builtin_amdgcn_s_sleep(8);
    }
}

// hidden [2L,B,H] -> state slot 3 ("t = -1")
__global__ void k_init(const float* __restrict__ hidden,
                       float* __restrict__ cbufF, __bf16* __restrict__ hb,
                       __bf16* __restrict__ cb) {
    const unsigned stride = gridDim.x * blockDim.x;
    for (unsigned i = blockIdx.x * blockDim.x + threadIdx.x; i < SLOT_ALL; i += stride) {
        float hv = hidden[i];
        float cv = hidden[SLOT_ALL + i];
        hb[3u * SLOT_ALL + i] = (__bf16)hv;
        cb[3u * SLOT_ALL + i] = (__bf16)cv;
        cbufF[3u * SLOT_ALL + i] = cv;
    }
}

// Persistent: grid (LL, 64) x 256. j = blockIdx.x, n0 = blockIdx.y*16.
// Wave w holds the k-quarter {4q+w} weight frags: wI/wF/wO[24], wC/wR[8] (one-time
// load from f32 inputs). Per t: wait 3 flag groups -> acquire fence -> 8 m-tiles
// (24 A-frag loads, 88 MFMAs, LDS partial exchange, consumer epilogue) -> flag store.
__global__ __launch_bounds__(256, 1) void k_persist(
    const float* __restrict__ x,
    const float* __restrict__ Wii,
    const float* __restrict__ Wic,
    const float* __restrict__ Wih,
    const float* __restrict__ bii,
    const float* __restrict__ bic,
    const float* __restrict__ bih,
    const float* __restrict__ Whh,
    const float* __restrict__ bhh,
    const float* __restrict__ Wir,
    float* __restrict__ cbufF,
    __bf16* __restrict__ hb,
    __bf16* __restrict__ cb,
    float* __restrict__ dout,
    int* __restrict__ done)
{
    __shared__ __align__(16) char smem[2 * 20480];   // 40 KiB partial exchange

    const int j = blockIdx.x;
    const int nwg = blockIdx.y;       // 0..63
    const int n0 = nwg * 16;
    const int tid = threadIdx.x;
    const int lane = tid & 63;
    const int w = tid >> 6;
    const int lrow = lane & 15;
    const int kgrp = lane >> 4;
    const int col = n0 + lrow;

    // ---- one-time weight fragment load (f32 -> bf16 in-register) ----
    bf16x8 wI[24], wF[24], wO[24], wC[8], wR[8];
    {
        const float* pi = Wii + (size_t)j * G3 * IN_D;   // [3072][1024]
        const float* ph = Wih + (size_t)j * G3 * HH;
        const float* pc = Wic + (size_t)j * G3 * HH;
        const float* pw = Whh + (size_t)j * HH * HH;
        const float* pr = Wir + (size_t)j * HH * IN_D;
        #pragma unroll
        for (int q = 0; q < 8; ++q) {
            const int kq = (4 * q + w) * 32 + kgrp * 8;
            wI[q]      = cvt8p(pi + (size_t)col * IN_D + kq);
            wI[8 + q]  = cvt8p(ph + (size_t)col * HH + kq);
            wI[16 + q] = cvt8p(pc + (size_t)col * HH + kq);
            wF[q]      = cvt8p(pi + (size_t)(col + 1024) * IN_D + kq);
            wF[8 + q]  = cvt8p(ph + (size_t)(col + 1024) * HH + kq);
            wF[16 + q] = cvt8p(pc + (size_t)(col + 1024) * HH + kq);
            wO[q]      = cvt8p(pi + (size_t)(col + 2048) * IN_D + kq);
            wO[8 + q]  = cvt8p(ph + (size_t)(col + 2048) * HH + kq);
            wO[16 + q] = cvt8p(pc + (size_t)(col + 2048) * HH + kq);
            wC[q] = cvt8p(pw + (size_t)col * HH + kq);
            wR[q] = cvt8p(pr + (size_t)col * IN_D + kq);
        }
    }
    const float b_i = bii[j * G3 + col] + bih[j * G3 + col] + bic[j * G3 + col];
    const float b_f = bii[j * G3 + 1024 + col] + bih[j * G3 + 1024 + col] + bic[j * G3 + 1024 + col];
    const float b_o = bii[j * G3 + 2048 + col] + bih[j * G3 + 2048 + col] + bic[j * G3 + 2048 + col];
    const float b_c = bhh[j * HH + col];

    const int ofs = 32 * w + 8 * kgrp;   // lane's k element offset within a 1024-row

    for (int t = 0; t < TT; ++t) {
        // ---- dependency waits (no global barrier) ----
        if (j > 0)               waitg(done + ((j - 1) * NFS + (t & 7)) * 64, t);
        if (t >= 1)              waitg(done + (j * NFS + ((t - 1) & 7)) * 64, t - 1);
        if (j < LL - 1 && t >= NSL) waitg(done + ((j + 1) * NFS + ((t - NSL) & 7)) * 64, t - NSL);
        __builtin_amdgcn_fence(__ATOMIC_ACQUIRE, "agent");   // inv stale L1/L2 (weights in regs: immune)

        const int sl = t & 3, slp = (t + 3) & 3;
        const float*  cFsrc = cbufF + (size_t)slp * SLOT_ALL + (size_t)j * SLOT;
        float*        cFdst = cbufF + (size_t)sl  * SLOT_ALL + (size_t)j * SLOT;
        const __bf16* hP = hb + (size_t)slp * SLOT_ALL + (size_t)j * SLOT;
        const __bf16* cP = cb + (size_t)slp * SLOT_ALL + (size_t)j * SLOT;
        const __bf16* outP = hb + (size_t)sl * SLOT_ALL + (size_t)(j - 1) * SLOT;  // j>0
        const float*  xP = x + (size_t)t * SLOT;                                    // j==0
        __bf16* hD = hb + (size_t)sl * SLOT_ALL + (size_t)j * SLOT;
        __bf16* cD = cb + (size_t)sl * SLOT_ALL + (size_t)j * SLOT;

        for (int m = 0; m < 8; ++m) {
            const int rowb = 16 * m + lrow;
            const __bf16* aO = outP + (size_t)rowb * HH + ofs;
            const float*  aX = xP   + (size_t)rowb * HH + ofs;
            const __bf16* aH = hP   + (size_t)rowb * HH + ofs;
            const __bf16* aC = cP   + (size_t)rowb * HH + ofs;

            f32x4 vI = {0,0,0,0}, vF = {0,0,0,0}, vO = {0,0,0,0},
                  vC = {0,0,0,0}, vR = {0,0,0,0};

            if (j > 0) {
                #pragma unroll
                for (int q = 0; q < 8; ++q) {
                    bf16x8 a = ldb(aO, 128 * q);
                    vI = mfma16(a, wI[q], vI); vF = mfma16(a, wF[q], vF);
                    vO = mfma16(a, wO[q], vO); vR = mfma16(a, wR[q], vR);
                }
            } else {
                #pragma unroll
                for (int q = 0; q < 8; ++q) {
                    bf16x8 a = cvt8p(aX + 128 * q);
                    vI = mfma16(a, wI[q], vI); vF = mfma16(a, wF[q], vF);
                    vO = mfma16(a, wO[q], vO); vR = mfma16(a, wR[q], vR);
                }
            }
            #pragma unroll
            for (int q = 0; q < 8; ++q) {
                bf16x8 a = ldb(aH, 128 * q);
                vI = mfma16(a, wI[8 + q], vI); vF = mfma16(a, wF[8 + q], vF);
                vO = mfma16(a, wO[8 + q], vO); vC = mfma16(a, wC[q], vC);
            }
            #pragma unroll
            for (int q = 0; q < 8; ++q) {
                bf16x8 a = ldb(aC, 128 * q);
                vI = mfma16(a, wI[16 + q], vI); vF = mfma16(a, wF[16 + q], vF);
                vO = mfma16(a, wO[16 + q], vO);
            }

            // exchange k-quarter partials through LDS
            float* exw = (float*)(smem + (m & 1) * 20480) + w * 1280 + lane * 4;
            *(f32x4*)(exw +    0) = vI;
            *(f32x4*)(exw +  256) = vF;
            *(f32x4*)(exw +  512) = vO;
            *(f32x4*)(exw +  768) = vC;
            *(f32x4*)(exw + 1024) = vR;
            __syncthreads();

            if (w == (m >> 1)) {
                f32x4 sI = {0,0,0,0}, sF = {0,0,0,0}, sO = {0,0,0,0},
                      sC = {0,0,0,0}, sR = {0,0,0,0};
                #pragma unroll
                for (int ww = 0; ww < 4; ++ww) {
                    const float* eb = (const float*)(smem + (m & 1) * 20480) + ww * 1280 + lane * 4;
                    sI += *(const f32x4*)(eb);
                    sF += *(const f32x4*)(eb + 256);
                    sO += *(const f32x4*)(eb + 512);
                    sC += *(const f32x4*)(eb + 768);
                    sR += *(const f32x4*)(eb + 1024);
                }
                #pragma unroll
                for (int r = 0; r < 4; ++r) {
                    const int row = 16 * m + 4 * kgrp + r;
                    const size_t o = (size_t)row * HH + col;
                    float iv = sI[r] + b_i;
                    float fv = sF[r] + b_f;
                    float ov = sO[r] + b_o;
                    float cg = tanh_fast(sC[r] + b_c);
                    float cold = cFsrc[o];
                    float cy = sigm(fv) * cold + sigm(iv) * cg;
                    float hy = sigm(ov) * (tanh_fast(cy) + sR[r]);
                    st_f32_sc(cFdst + o, cy);
                    st_b16_sc(hD + o, bf16bits(hy));
                    st_b16_sc(cD + o, bf16bits(cy));
                    if (j == LL - 1) st_f32_sc(dout + (size_t)t * SLOT + o, hy);
                    if (t == TT - 1) {
                        st_f32_sc(dout + (size_t)TT * SLOT + (size_t)j * SLOT + o, hy);
                        st_f32_sc(dout + (size_t)TT * SLOT + SLOT_ALL + (size_t)j * SLOT + o, cy);
                    }
                }
            }
        }

        // ---- signal: this WG finished time t (single-writer flag, no RMW) ----
        __syncthreads();   // all waves' sc stores drained (vmcnt0) before flag
        if (tid == 0) {
            __builtin_amdgcn_fence(__ATOMIC_RELEASE, "agent");   // cheap: nothing dirty
            int* fp = done + (j * NFS + (t & 7)) * 64 + nwg;
            asm volatile("global_store_dword %0, %1, off sc0 sc1" :: "v"(fp), "v"(t) : "memory");
        }
    }
}

extern "C" void kernel_launch(void* const* d_in, const int* in_sizes, int n_in,
                              void* d_out, int out_size, void* d_ws, size_t ws_size,
                              hipStream_t stream) {
    const float* x      = (const float*)d_in[0];
    const float* hidden = (const float*)d_in[1];
    const float* Wii    = (const float*)d_in[2];
    const float* Wic    = (const float*)d_in[3];
    const float* Wih    = (const float*)d_in[4];
    const float* bii    = (const float*)d_in[5];
    const float* bic    = (const float*)d_in[6];
    const float* bih    = (const float*)d_in[7];
    const float* Whh    = (const float*)d_in[8];
    const float* bhh    = (const float*)d_in[9];
    const float* Wir    = (const float*)d_in[10];
    float* out = (float*)d_out;

    // ws layout (bytes):
    //   cbufF @ 0         8,388,608   (4 slots x L x B x H f32)
    //   hb    @ 8388608   4,194,304   (4 slots, bf16)
    //   cb    @ 12582912  4,194,304
    //   done  @ 16777216      8,192   (L x 8 slots x 64 WGs, int)
    char* ws = (char*)d_ws;
    float*  cbufF = (float*)(ws);
    __bf16* hb    = (__bf16*)(ws + 8388608);
    __bf16* cb    = (__bf16*)(ws + 12582912);
    int*    done  = (int*)(ws + 16777216);

    hipMemsetAsync(done, 0xFF, LL * NFS * 64 * sizeof(int), stream);   // all flags = -1
    k_init<<<1024, 256, 0, stream>>>(hidden, cbufF, hb, cb);

    dim3 grid(LL, 64), block(256);
    k_persist<<<grid, block, 0, stream>>>(x, Wii, Wic, Wih, bii, bic, bih,
                                          Whh, bhh, Wir, cbufF, hb, cb, out, done);
}

// Round 9
// 32508.884 us; speedup vs baseline: 1.5725x; 1.3976x over previous
//
#include <hip/hip_runtime.h>

// ResLSTM: T=512, B=128, IN=H=1024, L=4.
// R9: weights-in-registers persistent kernel, flag-pipelined (R8 protocol), with
// R8's three serializers removed:
//  - NO per-t acquire fence (was 131k L2-invalidates thrashing panels). Shared
//    state read via sc0sc1 LOADS (coherence-point, no side effects).
//  - WG-private f32 c-carry via NORMAL cached ld/st (stays in local L2).
//  - 8 waves/WG with k-eighth weight split (176 weight VGPRs -> 2 waves/SIMD),
//    raw s_barrier m-loop, counted vmcnt(8/4/0) phases, epilogue after the loop,
//    single vmcnt(0) drain per t before the flag store.

#define TT 512
#define BB 128
#define IN_D 1024
#define HH 1024
#define LL 4
#define G3 3072
#define SLOT (BB * HH)        // 131072
#define SLOT_ALL (LL * SLOT)  // 524288
#define NSL 4                 // state time-slots
#define NFS 8                 // flag time-slots

typedef __attribute__((ext_vector_type(8))) __bf16 bf16x8;
typedef __attribute__((ext_vector_type(4))) float f32x4;

__device__ __forceinline__ f32x4 mfma16(bf16x8 a, bf16x8 b, f32x4 c) {
    return __builtin_amdgcn_mfma_f32_16x16x32_bf16(a, b, c, 0, 0, 0);
}
__device__ __forceinline__ bf16x8 cvt8(float4 u, float4 v) {
    bf16x8 r;
    r[0] = (__bf16)u.x; r[1] = (__bf16)u.y; r[2] = (__bf16)u.z; r[3] = (__bf16)u.w;
    r[4] = (__bf16)v.x; r[5] = (__bf16)v.y; r[6] = (__bf16)v.z; r[7] = (__bf16)v.w;
    return r;
}
__device__ __forceinline__ bf16x8 cvt8p(const float* p) {
    float4 u = *reinterpret_cast<const float4*>(p);
    float4 v = *reinterpret_cast<const float4*>(p + 4);
    return cvt8(u, v);
}
__device__ __forceinline__ float sigm(float v) { return 1.f / (1.f + __expf(-v)); }
__device__ __forceinline__ float tanh_fast(float v) { return 1.f - 2.f / (1.f + __expf(2.f * v)); }
__device__ __forceinline__ unsigned bf16bits(float f) {
    __bf16 h = (__bf16)f;
    return (unsigned)__builtin_bit_cast(unsigned short, h);
}

// coherence-point ops (no cache-invalidate side effects)
__device__ __forceinline__ bf16x8 ld_sc16(const __bf16* p) {
    bf16x8 r;
    asm volatile("global_load_dwordx4 %0, %1, off sc0 sc1" : "=v"(r) : "v"(p) : "memory");
    return r;
}
__device__ __forceinline__ void st_f32_sc(float* p, float v) {
    asm volatile("global_store_dword %0, %1, off sc0 sc1" :: "v"(p), "v"(v) : "memory");
}
__device__ __forceinline__ void st_b16_sc(__bf16* p, unsigned v) {
    asm volatile("global_store_short %0, %1, off sc0 sc1" :: "v"(p), "v"(v) : "memory");
}
#define VMW(N) { asm volatile("s_waitcnt vmcnt(" #N ")" ::: "memory"); \
                 __builtin_amdgcn_sched_barrier(0); }
#define LGKW   { asm volatile("s_waitcnt lgkmcnt(0)" ::: "memory"); \
                 __builtin_amdgcn_sched_barrier(0); }

// 64-lane flag-group wait: lane i polls flags[i]
__device__ __forceinline__ void waitg(const int* p, int tgt) {
    const int* q = p + (threadIdx.x & 63);
    for (;;) {
        int v;
        asm volatile("global_load_dword %0, %1, off sc0 sc1\n\ts_waitcnt vmcnt(0)"
                     : "=v"(v) : "v"(q) : "memory");
        if (__all(v >= tgt)) return;
        __builtin_amdgcn_s_sleep(4);
    }
}

// hidden [2L,B,H] -> state slot 3 ("t = -1")
__global__ void k_init(const float* __restrict__ hidden,
                       float* __restrict__ cbufF, __bf16* __restrict__ hb,
                       __bf16* __restrict__ cb) {
    const unsigned stride = gridDim.x * blockDim.x;
    for (unsigned i = blockIdx.x * blockDim.x + threadIdx.x; i < SLOT_ALL; i += stride) {
        float hv = hidden[i];
        float cv = hidden[SLOT_ALL + i];
        hb[3u * SLOT_ALL + i] = (__bf16)hv;
        cb[3u * SLOT_ALL + i] = (__bf16)cv;
        cbufF[3u * SLOT_ALL + i] = cv;
    }
}

// Persistent: grid (LL, 64) x 512 (8 waves). j = blockIdx.x, n0 = blockIdx.y*16.
// Wave w holds the k-eighth [128w,128w+128) weight frags of each K-segment:
// wIo/wFo/wOo/wR (out-seg), wIh/wFh/wOh/wC (h-seg), wIc/wFc/wOc (c-seg) = 44 frags.
// Per t: wave0 waits 3 flag groups -> 8 m-tiles {12 sc A-loads, counted-vmcnt
// phases, 44 MFMAs, LDS partial exchange (consumer wave m keeps sums in regs)}
// -> per-wave epilogue (m=w) -> vmcnt(0) -> barrier -> flag.
__global__ __launch_bounds__(512, 2) void k_persist(
    const float* __restrict__ x,
    const float* __restrict__ Wii,
    const float* __restrict__ Wic,
    const float* __restrict__ Wih,
    const float* __restrict__ bii,
    const float* __restrict__ bic,
    const float* __restrict__ bih,
    const float* __restrict__ Whh,
    const float* __restrict__ bhh,
    const float* __restrict__ Wir,
    float* __restrict__ cbufF,
    __bf16* __restrict__ hb,
    __bf16* __restrict__ cb,
    float* __restrict__ dout,
    int* __restrict__ done)
{
    __shared__ __align__(16) float smem[8 * 5 * 64 * 4];   // 40 KiB

    const int j = blockIdx.x;
    const int nwg = blockIdx.y;
    const int n0 = nwg * 16;
    const int tid = threadIdx.x;
    const int lane = tid & 63;
    const int w = tid >> 6;            // wave 0..7
    const int lrow = lane & 15;
    const int kgrp = lane >> 4;
    const int col = n0 + lrow;
    const int kbase = w * 128 + kgrp * 8;   // lane's k-eighth base within a 1024-seg

    // ---- one-time weight fragment load (f32 -> bf16 in-register), 44 frags ----
    bf16x8 wIo[4], wFo[4], wOo[4], wR4[4];
    bf16x8 wIh[4], wFh[4], wOh[4], wC4[4];
    bf16x8 wIc[4], wFc[4], wOc[4];
    {
        const float* pi = Wii + (size_t)j * G3 * IN_D;
        const float* ph = Wih + (size_t)j * G3 * HH;
        const float* pc = Wic + (size_t)j * G3 * HH;
        const float* pw = Whh + (size_t)j * HH * HH;
        const float* pr = Wir + (size_t)j * HH * IN_D;
        #pragma unroll
        for (int q = 0; q < 4; ++q) {
            const int ko = kbase + 32 * q;
            wIo[q] = cvt8p(pi + (size_t)col * IN_D + ko);
            wIh[q] = cvt8p(ph + (size_t)col * HH + ko);
            wIc[q] = cvt8p(pc + (size_t)col * HH + ko);
            wFo[q] = cvt8p(pi + (size_t)(col + 1024) * IN_D + ko);
            wFh[q] = cvt8p(ph + (size_t)(col + 1024) * HH + ko);
            wFc[q] = cvt8p(pc + (size_t)(col + 1024) * HH + ko);
            wOo[q] = cvt8p(pi + (size_t)(col + 2048) * IN_D + ko);
            wOh[q] = cvt8p(ph + (size_t)(col + 2048) * HH + ko);
            wOc[q] = cvt8p(pc + (size_t)(col + 2048) * HH + ko);
            wC4[q] = cvt8p(pw + (size_t)col * HH + ko);
            wR4[q] = cvt8p(pr + (size_t)col * IN_D + ko);
        }
    }
    const float b_i = bii[j * G3 + col] + bih[j * G3 + col] + bic[j * G3 + col];
    const float b_f = bii[j * G3 + 1024 + col] + bih[j * G3 + 1024 + col] + bic[j * G3 + 1024 + col];
    const float b_o = bii[j * G3 + 2048 + col] + bih[j * G3 + 2048 + col] + bic[j * G3 + 2048 + col];
    const float b_c = bhh[j * HH + col];

    f32x4* exch = (f32x4*)smem;   // [wave][acc][lane]

    for (int t = 0; t < TT; ++t) {
        // ---- dependency waits (wave 0 polls, others park at barrier) ----
        if (w == 0) {
            if (j > 0)                  waitg(done + ((j - 1) * NFS + (t & 7)) * 64, t);
            if (t >= 1)                 waitg(done + (j * NFS + ((t - 1) & 7)) * 64, t - 1);
            if (j < LL - 1 && t >= NSL) waitg(done + ((j + 1) * NFS + ((t - NSL) & 7)) * 64, t - NSL);
        }
        __builtin_amdgcn_s_barrier();

        const int sl = t & 3, slp = (t + 3) & 3;
        const float*  cFsrc = cbufF + (size_t)slp * SLOT_ALL + (size_t)j * SLOT;  // WG-private
        float*        cFdst = cbufF + (size_t)sl  * SLOT_ALL + (size_t)j * SLOT;
        const __bf16* hP = hb + (size_t)slp * SLOT_ALL + (size_t)j * SLOT;
        const __bf16* cP = cb + (size_t)slp * SLOT_ALL + (size_t)j * SLOT;
        const __bf16* outP = hb + (size_t)sl * SLOT_ALL + (size_t)(j - 1) * SLOT;  // j>0
        const float*  xP = x + (size_t)t * SLOT;                                    // j==0
        __bf16* hD = hb + (size_t)sl * SLOT_ALL + (size_t)j * SLOT;
        __bf16* cD = cb + (size_t)sl * SLOT_ALL + (size_t)j * SLOT;

        f32x4 sI, sF, sO, sC, sR;   // consumer sums for m == w (set in loop)

        for (int m = 0; m < 8; ++m) {
            const size_t rofs = (size_t)(16 * m + lrow) * HH + kbase;
            f32x4 vI = {0,0,0,0}, vF = {0,0,0,0}, vO = {0,0,0,0},
                  vC = {0,0,0,0}, vR = {0,0,0,0};

            if (j > 0) {
                const __bf16* bO = outP + rofs;
                const __bf16* bH = hP + rofs;
                const __bf16* bC = cP + rofs;
                bf16x8 aO0 = ld_sc16(bO), aO1 = ld_sc16(bO + 32), aO2 = ld_sc16(bO + 64), aO3 = ld_sc16(bO + 96);
                bf16x8 aH0 = ld_sc16(bH), aH1 = ld_sc16(bH + 32), aH2 = ld_sc16(bH + 64), aH3 = ld_sc16(bH + 96);
                bf16x8 aC0 = ld_sc16(bC), aC1 = ld_sc16(bC + 32), aC2 = ld_sc16(bC + 64), aC3 = ld_sc16(bC + 96);
                VMW(8)
                vI = mfma16(aO0, wIo[0], vI); vF = mfma16(aO0, wFo[0], vF); vO = mfma16(aO0, wOo[0], vO); vR = mfma16(aO0, wR4[0], vR);
                vI = mfma16(aO1, wIo[1], vI); vF = mfma16(aO1, wFo[1], vF); vO = mfma16(aO1, wOo[1], vO); vR = mfma16(aO1, wR4[1], vR);
                vI = mfma16(aO2, wIo[2], vI); vF = mfma16(aO2, wFo[2], vF); vO = mfma16(aO2, wOo[2], vO); vR = mfma16(aO2, wR4[2], vR);
                vI = mfma16(aO3, wIo[3], vI); vF = mfma16(aO3, wFo[3], vF); vO = mfma16(aO3, wOo[3], vO); vR = mfma16(aO3, wR4[3], vR);
                VMW(4)
                vI = mfma16(aH0, wIh[0], vI); vF = mfma16(aH0, wFh[0], vF); vO = mfma16(aH0, wOh[0], vO); vC = mfma16(aH0, wC4[0], vC);
                vI = mfma16(aH1, wIh[1], vI); vF = mfma16(aH1, wFh[1], vF); vO = mfma16(aH1, wOh[1], vO); vC = mfma16(aH1, wC4[1], vC);
                vI = mfma16(aH2, wIh[2], vI); vF = mfma16(aH2, wFh[2], vF); vO = mfma16(aH2, wOh[2], vO); vC = mfma16(aH2, wC4[2], vC);
                vI = mfma16(aH3, wIh[3], vI); vF = mfma16(aH3, wFh[3], vF); vO = mfma16(aH3, wOh[3], vO); vC = mfma16(aH3, wC4[3], vC);
                VMW(0)
                vI = mfma16(aC0, wIc[0], vI); vF = mfma16(aC0, wFc[0], vF); vO = mfma16(aC0, wOc[0], vO);
                vI = mfma16(aC1, wIc[1], vI); vF = mfma16(aC1, wFc[1], vF); vO = mfma16(aC1, wOc[1], vO);
                vI = mfma16(aC2, wIc[2], vI); vF = mfma16(aC2, wFc[2], vF); vO = mfma16(aC2, wOc[2], vO);
                vI = mfma16(aC3, wIc[3], vI); vF = mfma16(aC3, wFc[3], vF); vO = mfma16(aC3, wOc[3], vO);
            } else {
                const float* bX = xP + rofs;
                const __bf16* bH = hP + rofs;
                const __bf16* bC = cP + rofs;
                bf16x8 aH0 = ld_sc16(bH), aH1 = ld_sc16(bH + 32), aH2 = ld_sc16(bH + 64), aH3 = ld_sc16(bH + 96);
                bf16x8 aC0 = ld_sc16(bC), aC1 = ld_sc16(bC + 32), aC2 = ld_sc16(bC + 64), aC3 = ld_sc16(bC + 96);
                bf16x8 aO0 = cvt8p(bX), aO1 = cvt8p(bX + 32), aO2 = cvt8p(bX + 64), aO3 = cvt8p(bX + 96);
                vI = mfma16(aO0, wIo[0], vI); vF = mfma16(aO0, wFo[0], vF); vO = mfma16(aO0, wOo[0], vO); vR = mfma16(aO0, wR4[0], vR);
                vI = mfma16(aO1, wIo[1], vI); vF = mfma16(aO1, wFo[1], vF); vO = mfma16(aO1, wOo[1], vO); vR = mfma16(aO1, wR4[1], vR);
                vI = mfma16(aO2, wIo[2], vI); vF = mfma16(aO2, wFo[2], vF); vO = mfma16(aO2, wOo[2], vO); vR = mfma16(aO2, wR4[2], vR);
                vI = mfma16(aO3, wIo[3], vI); vF = mfma16(aO3, wFo[3], vF); vO = mfma16(aO3, wOo[3], vO); vR = mfma16(aO3, wR4[3], vR);
                VMW(0)
                vI = mfma16(aH0, wIh[0], vI); vF = mfma16(aH0, wFh[0], vF); vO = mfma16(aH0, wOh[0], vO); vC = mfma16(aH0, wC4[0], vC);
                vI = mfma16(aH1, wIh[1], vI); vF = mfma16(aH1, wFh[1], vF); vO = mfma16(aH1, wOh[1], vO); vC = mfma16(aH1, wC4[1], vC);
                vI = mfma16(aH2, wIh[2], vI); vF = mfma16(aH2, wFh[2], vF); vO = mfma16(aH2, wOh[2], vO); vC = mfma16(aH2, wC4[2], vC);
                vI = mfma16(aH3, wIh[3], vI); vF = mfma16(aH3, wFh[3], vF); vO = mfma16(aH3, wOh[3], vO); vC = mfma16(aH3, wC4[3], vC);
                vI = mfma16(aC0, wIc[0], vI); vF = mfma16(aC0, wFc[0], vF); vO = mfma16(aC0, wOc[0], vO);
                vI = mfma16(aC1, wIc[1], vI); vF = mfma16(aC1, wFc[1], vF); vO = mfma16(aC1, wOc[1], vO);
                vI = mfma16(aC2, wIc[2], vI); vF = mfma16(aC2, wFc[2], vF); vO = mfma16(aC2, wOc[2], vO);
                vI = mfma16(aC3, wIc[3], vI); vF = mfma16(aC3, wFc[3], vF); vO = mfma16(aC3, wOc[3], vO);
            }

            // ---- exchange k-eighth partials through LDS ----
            exch[(w * 5 + 0) * 64 + lane] = vI;
            exch[(w * 5 + 1) * 64 + lane] = vF;
            exch[(w * 5 + 2) * 64 + lane] = vO;
            exch[(w * 5 + 3) * 64 + lane] = vC;
            exch[(w * 5 + 4) * 64 + lane] = vR;
            LGKW
            __builtin_amdgcn_s_barrier();
            if (w == m) {
                sI = (f32x4){0,0,0,0}; sF = (f32x4){0,0,0,0}; sO = (f32x4){0,0,0,0};
                sC = (f32x4){0,0,0,0}; sR = (f32x4){0,0,0,0};
                #pragma unroll
                for (int ww = 0; ww < 8; ++ww) {
                    sI += exch[(ww * 5 + 0) * 64 + lane];
                    sF += exch[(ww * 5 + 1) * 64 + lane];
                    sO += exch[(ww * 5 + 2) * 64 + lane];
                    sC += exch[(ww * 5 + 3) * 64 + lane];
                    sR += exch[(ww * 5 + 4) * 64 + lane];
                }
                LGKW
            }
            __builtin_amdgcn_s_barrier();
        }

        // ---- per-wave epilogue: wave w owns m-tile w (rows 16w..16w+15) ----
        {
            #pragma unroll
            for (int r = 0; r < 4; ++r) {
                const int row = 16 * w + 4 * kgrp + r;
                const size_t o = (size_t)row * HH + col;
                float iv = sI[r] + b_i;
                float fv = sF[r] + b_f;
                float ov = sO[r] + b_o;
                float cg = tanh_fast(sC[r] + b_c);
                float cold = cFsrc[o];                 // normal load (WG-private, L2)
                float cy = sigm(fv) * cold + sigm(iv) * cg;
                float hy = sigm(ov) * (tanh_fast(cy) + sR[r]);
                cFdst[o] = cy;                          // normal store (WG-private)
                st_b16_sc(hD + o, bf16bits(hy));
                st_b16_sc(cD + o, bf16bits(cy));
                if (j == LL - 1) dout[(size_t)t * SLOT + o] = hy;
                if (t == TT - 1) {
                    dout[(size_t)TT * SLOT + (size_t)j * SLOT + o] = hy;
                    dout[(size_t)TT * SLOT + SLOT_ALL + (size_t)j * SLOT + o] = cy;
                }
            }
        }

        // ---- signal: all sc stores retired, then single-writer flag ----
        asm volatile("s_waitcnt vmcnt(0)" ::: "memory");
        __builtin_amdgcn_s_barrier();
        if (tid == 0) {
            int* fp = done + (j * NFS + (t & 7)) * 64 + nwg;
            asm volatile("global_store_dword %0, %1, off sc0 sc1" :: "v"(fp), "v"(t) : "memory");
        }
    }
}

extern "C" void kernel_launch(void* const* d_in, const int* in_sizes, int n_in,
                              void* d_out, int out_size, void* d_ws, size_t ws_size,
                              hipStream_t stream) {
    const float* x      = (const float*)d_in[0];
    const float* hidden = (const float*)d_in[1];
    const float* Wii    = (const float*)d_in[2];
    const float* Wic    = (const float*)d_in[3];
    const float* Wih    = (const float*)d_in[4];
    const float* bii    = (const float*)d_in[5];
    const float* bic    = (const float*)d_in[6];
    const float* bih    = (const float*)d_in[7];
    const float* Whh    = (const float*)d_in[8];
    const float* bhh    = (const float*)d_in[9];
    const float* Wir    = (const float*)d_in[10];
    float* out = (float*)d_out;

    // ws layout (bytes):
    //   cbufF @ 0         8,388,608   (4 slots x L x B x H f32, WG-private carry)
    //   hb    @ 8388608   4,194,304   (4 slots, bf16, shared via sc ops)
    //   cb    @ 12582912  4,194,304
    //   done  @ 16777216      8,192
    char* ws = (char*)d_ws;
    float*  cbufF = (float*)(ws);
    __bf16* hb    = (__bf16*)(ws + 8388608);
    __bf16* cb    = (__bf16*)(ws + 12582912);
    int*    done  = (int*)(ws + 16777216);

    hipMemsetAsync(done, 0xFF, LL * NFS * 64 * sizeof(int), stream);
    k_init<<<1024, 256, 0, stream>>>(hidden, cbufF, hb, cb);

    dim3 grid(LL, 64), block(512);
    k_persist<<<grid, block, 0, stream>>>(x, Wii, Wic, Wih, bii, bic, bih,
                                          Whh, bhh, Wir, cbufF, hb, cb, out, done);
}